// Round 5
// baseline (346.097 us; speedup 1.0000x reference)
//
#include <hip/hip_runtime.h>
#include <hip/hip_bf16.h>

// Welford over batch dim: x [B=64, C=256, H=56, W=56] fp32 -> out [2, C, H, W]
// out[0,:] = mean m, out[1,:] = M2 s (var = s/(n-1)). Bit-exact sequential
// recurrence (absmax 0.0 in R2/R4).
//
// ATTRIBUTION EXPERIMENT (R5): launch the identical kernel 3x. Kernel is
// idempotent, so pass/absmax are unchanged; dur_us delta vs R4 (278 us)
// gives 2x the per-launch kernel time, resolving whether the kernel is at
// the ~35-45 us memory floor (harness dominates) or ~90 us (recoverable).

#define B_SAMPLES 64

__global__ __launch_bounds__(256) void welford_kernel(
    const float2* __restrict__ x, float2* __restrict__ out, int chw2) {
  int idx = blockIdx.x * blockDim.x + threadIdx.x;
  if (idx >= chw2) return;

  float2 m = make_float2(0.f, 0.f);
  float2 s = make_float2(0.f, 0.f);

  const float2* p = x + idx;

#pragma unroll 16
  for (int b = 0; b < B_SAMPLES; ++b) {
    float2 xi = p[(size_t)b * (size_t)chw2];
    float n = (float)(b + 1);

    float d;
    d = xi.x - m.x; m.x += d / n; s.x += d * (xi.x - m.x);
    d = xi.y - m.y; m.y += d / n; s.y += d * (xi.y - m.y);
  }

  out[idx] = m;          // mean -> out[0, chw]
  out[idx + chw2] = s;   // M2   -> out[1, chw]
}

extern "C" void kernel_launch(void* const* d_in, const int* in_sizes, int n_in,
                              void* d_out, int out_size, void* d_ws, size_t ws_size,
                              hipStream_t stream) {
  const float* x = (const float*)d_in[0];
  float* out = (float*)d_out;

  const int total = in_sizes[0];        // B * C * H * W = 51380224
  const int chw = total / B_SAMPLES;    // 802816
  const int chw2 = chw / 2;             // 401408

  const int block = 256;
  const int grid = (chw2 + block - 1) / block;  // 1568

  // 3 identical idempotent launches: dur_us delta vs single-launch baseline
  // = 2x per-launch kernel time (launches 2-3 are L3-warm).
  for (int rep = 0; rep < 3; ++rep) {
    welford_kernel<<<grid, block, 0, stream>>>(
        (const float2*)x, (float2*)out, chw2);
  }
}

// Round 6
// 279.146 us; speedup vs baseline: 1.2398x; 1.2398x over previous
//
#include <hip/hip_runtime.h>
#include <hip/hip_bf16.h>

// Welford over batch dim: x [B=64, C=256, H=56, W=56] fp32 -> out [2, C, H, W]
// out[0,:] = running mean m, out[1,:] = M2 accumulator s (var = s/(n-1)).
// One thread per 2 contiguous feature positions (float2); exact sequential
// recurrence over B=64 samples in registers, matching reference op order:
//   n += 1; d = xi - m; m += d / n; s += d * (xi - m)   (bit-exact, absmax 0)
//
// ROOFLINE (established R5): per-launch kernel time ~34 us, measured via a
// 3x-launch A/B (dur_us 277.9 -> 346.1, delta/2 = 34.1 us), which equals the
// streaming floor 212 MB / 6.3 TB/s. The remaining ~244 us of the timed
// figure is harness poison/restore traffic (fillBufferAligned at ~85% HBM
// peak in the profile), not kernel time. Occupancy (12 vs 24.5 waves/CU)
// and the fp32 divide chain are both confirmed non-factors.

#define B_SAMPLES 64

__global__ __launch_bounds__(256) void welford_kernel(
    const float2* __restrict__ x, float2* __restrict__ out, int chw2) {
  int idx = blockIdx.x * blockDim.x + threadIdx.x;
  if (idx >= chw2) return;

  float2 m = make_float2(0.f, 0.f);
  float2 s = make_float2(0.f, 0.f);

  const float2* p = x + idx;

#pragma unroll 16
  for (int b = 0; b < B_SAMPLES; ++b) {
    float2 xi = p[(size_t)b * (size_t)chw2];
    float n = (float)(b + 1);

    float d;
    d = xi.x - m.x; m.x += d / n; s.x += d * (xi.x - m.x);
    d = xi.y - m.y; m.y += d / n; s.y += d * (xi.y - m.y);
  }

  out[idx] = m;          // mean -> out[0, chw]
  out[idx + chw2] = s;   // M2   -> out[1, chw]
}

extern "C" void kernel_launch(void* const* d_in, const int* in_sizes, int n_in,
                              void* d_out, int out_size, void* d_ws, size_t ws_size,
                              hipStream_t stream) {
  const float* x = (const float*)d_in[0];
  float* out = (float*)d_out;

  const int total = in_sizes[0];        // B * C * H * W = 51380224
  const int chw = total / B_SAMPLES;    // 802816
  const int chw2 = chw / 2;             // 401408

  const int block = 256;
  const int grid = (chw2 + block - 1) / block;  // 1568
  welford_kernel<<<grid, block, 0, stream>>>(
      (const float2*)x, (float2*)out, chw2);
}